// Round 3
// baseline (4844.817 us; speedup 1.0000x reference)
//
#include <hip/hip_runtime.h>

// B=128, S=1024, F_IN=128, H=256, BB=256, F_OUT=128
#define Bn   128
#define Sn   1024
#define FIN  128
#define Hn   256
#define FOUT 128
#define KBB  384
#define NT1  1024   // phase-1 threads (16 waves)

// H-loop chunk partition (32 chunks of 16B per thread):
//   c in [0,NV)        -> VGPR-resident (loaded once, asm-pinned)  NV*4 VGPRs
//   c in [NV,NV+NL)    -> LDS-resident (loaded once)               NL*16KB dyn smem
//   c in [NV+NL,32)    -> streamed from L2 every step
// NV=12: 48 weight VGPRs + ~60 working < 128/wave hard cap (1024-thr WG).
// Round-2 lesson: NV=16 (64 regs) made the allocator sink ALL resident loads
// back into the loop (VGPR_Count=64 observed) -> everything streamed.
#define NV 12
#define NL 8
#define DYN_SMEM (NL * 1024 * 8 * 2)   // 131072 bytes

// packed weight layout in d_ws (halves):
//   Wb_p [48][256][8]  -> 98304
//   W4_p [32][1024][8] -> 262144   (N = [ff1|ff2|ta|tb])
//   Wo_p [32][128][8]  -> 32768
//   hbuf [B*S*H] fp16  -> 33554432 (only if ws_size permits)
#define WB_OFF 0
#define W4_OFF 98304
#define WO_OFF 360448
#define WS_HALVES 393216
#define HBUF_OFF WS_HALVES
#define WS_SPLIT_BYTES ((size_t)(WS_HALVES + (size_t)Bn * Sn * Hn) * 2)

typedef _Float16 h2 __attribute__((ext_vector_type(2)));
typedef _Float16 h8 __attribute__((ext_vector_type(8)));

__device__ __forceinline__ float dot2f(h2 a, h2 b, float c) {
#if __has_builtin(__builtin_amdgcn_fdot2)
  return __builtin_amdgcn_fdot2(a, b, c, false);   // v_dot2_f32_f16
#else
  return c + (float)a[0] * (float)b[0] + (float)a[1] * (float)b[1];
#endif
}
__device__ __forceinline__ void dot8_4(h8 v, h8 w, float& c0, float& c1, float& c2, float& c3) {
  h2 v0 = {v[0], v[1]}, v1 = {v[2], v[3]}, v2 = {v[4], v[5]}, v3 = {v[6], v[7]};
  h2 w0 = {w[0], w[1]}, w1 = {w[2], w[3]}, w2 = {w[4], w[5]}, w3 = {w[6], w[7]};
  c0 = dot2f(v0, w0, c0); c1 = dot2f(v1, w1, c1);
  c2 = dot2f(v2, w2, c2); c3 = dot2f(v3, w3, c3);
}

// fp32 -> fp16 packing (verified layout)
__global__ __launch_bounds__(256) void pack_w(
    const float* __restrict__ Wb, const float* __restrict__ W1,
    const float* __restrict__ W2, const float* __restrict__ W3,
    const float* __restrict__ W4, const float* __restrict__ Wo,
    _Float16* __restrict__ ws) {
  int p = blockIdx.x * 256 + threadIdx.x;
  if (p >= WS_HALVES) return;
  float v;
  if (p < W4_OFF) {                       // backbone [384,256] row-major
    int r = p & 7, j = (p >> 3) & 255;
    int k = ((p >> 11) << 3) | r;
    v = Wb[k * 256 + j];
  } else if (p < WO_OFF) {                // heads concat: N = [ff1|ff2|ta|tb]
    int q = p - W4_OFF;
    int r = q & 7, j = (q >> 3) & 1023;
    int k = ((q >> 13) << 3) | r;
    int jj = j & 255;
    const float* Ws = (j < 256) ? W1 : (j < 512) ? W2 : (j < 768) ? W3 : W4;
    v = Ws[k * 256 + jj];
  } else {                                // Wout [256,128]
    int q = p - WO_OFF;
    int r = q & 7, j = (q >> 3) & 127;
    int k = ((q >> 10) << 3) | r;
    v = Wo[k * 128 + j];
  }
  ws[p] = (_Float16)v;
}

// Phase 1: one 1024-thread WG per batch element. Measured bottleneck is the
// per-CU L2 port (~56 B/cy): time/step ~= streamed_weight_bytes / 56.
// Residency plan: 12 H-chunks in VGPRs (asm-pinned so the compiler cannot
// rematerialize the loads inside the loop) + 8 H-chunks in LDS (128 KB,
// loaded once, reused for all 1024 steps). Streamed/step: 12 Z-chunks
// (192 KB) + 12 H-chunks (192 KB) = 384 KB -> ~2.9 us/step stream floor.
template <int INLINE_Y>
__global__ __launch_bounds__(NT1, 4) void cfc3(
    const float* __restrict__ x, const float* __restrict__ ts,
    const float* __restrict__ bb, const float* __restrict__ bf1,
    const float* __restrict__ bf2, const float* __restrict__ bta,
    const float* __restrict__ btb, const float* __restrict__ bo,
    _Float16* __restrict__ ws, float* __restrict__ out) {
  __shared__ __align__(16) _Float16 xh[KBB];   // [0,128): x_t  [128,384): h
  __shared__ __align__(16) _Float16 zf[Hn];
  __shared__ float tsb[Sn];
  __shared__ float scrZ[768];
  __shared__ float scrH[768];
  __shared__ float scrY[896];
  extern __shared__ _Float16 sWH[];            // [NL][1024][8] halves

  const int tid = threadIdx.x;
  const int b = blockIdx.x;
  const _Float16* Wb_p = ws + WB_OFF;
  const _Float16* W4_p = ws + W4_OFF;
  const _Float16* Wo_p = ws + WO_OFF;
  _Float16* hbuf = ws + HBUF_OFF;

  const float* xrow  = x  + (size_t)b * Sn * FIN;
  const float* tsrow = ts + (size_t)b * Sn;
  float*       orow  = out + (size_t)b * Sn * FOUT;

  // ---- per-role constants ----
  const int jq = tid & 255;          // column within a 256 group
  const int kw = tid >> 8;           // Z K-split group (0..3), wave-uniform
  const float bbj = (tid < 256) ? bb[tid] : 0.f;
  const float bH = (kw == 0 ? bf1 : kw == 1 ? bf2 : kw == 2 ? bta : btb)[jq];
  const int jY = tid & 127, kq = tid >> 7;
  const float boj = (tid < 128) ? bo[tid] : 0.f;

  const _Float16* gZ = Wb_p + ((size_t)(kw * 12) * 256 + jq) * 8;  // 12 chunks
  const _Float16* gH = W4_p + (size_t)tid * 8;                     // 32 chunks
  const _Float16* gY = Wo_p + ((size_t)(kq * 4) * 128 + jY) * 8;   // 4 chunks

  // ---- one-time weight residency ----
  h8 wH[NV];                                  // chunks [0,NV) in VGPRs
#pragma unroll
  for (int c = 0; c < NV; ++c) wH[c] = *(const h8*)(gH + (size_t)c * 8192);
  // Pin: make each value opaque to the optimizer so the loads cannot be
  // rematerialized (sunk) into the step loop. Values must stay in VGPRs.
#pragma unroll
  for (int c = 0; c < NV; ++c) asm volatile("" : "+v"(wH[c]));
#pragma unroll
  for (int cc = 0; cc < NL; ++cc)             // chunks [NV,NV+NL) in LDS
    *(h8*)(sWH + (size_t)cc * 8192 + tid * 8) =
        *(const h8*)(gH + (size_t)(NV + cc) * 8192);

  // ---- one-time staging ----
  tsb[tid] = tsrow[tid];                       // NT1 == Sn
  if (tid < 128) ((unsigned*)xh)[64 + tid] = 0;   // h0 = 0 (halves [128,384))
  if (tid < 64) {                              // x(0)
    float2 xv = *(const float2*)(xrow + 2 * tid);
    h2 p; p[0] = (_Float16)xv.x; p[1] = (_Float16)xv.y;
    *(h2*)&xh[2 * tid] = p;
  }
  __syncthreads();

  for (int st = 0; st < Sn; ++st) {
    // x(t+1) prefetch (wave 15)
    float2 xv; xv.x = 0.f; xv.y = 0.f;
    if (tid >= 960 && st + 1 < Sn)
      xv = *(const float2*)(xrow + (size_t)(st + 1) * FIN + 2 * (tid - 960));

    // ---- Z: z = tanh([x,h] @ Wb + bb); K=384 split into 4 wave-groups ----
    float a0 = 0.f, a1 = 0.f, a2 = 0.f, a3 = 0.f;
#pragma unroll 4
    for (int c = 0; c < 12; ++c) {
      h8 v = *(const h8*)&xh[(kw * 12 + c) * 8];        // LDS broadcast
      h8 w = *(const h8*)(gZ + (size_t)c * 2048);       // 1 KB/wave contiguous
      dot8_4(v, w, a0, a1, a2, a3);
    }
    float zs = a0 + a1 + a2 + a3;
    if (tid >= 256) scrZ[tid - 256] = zs;
    __syncthreads();                     // B1: Z xh-reads done, scrZ ready
    if (tid < 256) {
      float zp = zs + scrZ[tid] + scrZ[256 + tid] + scrZ[512 + tid] + bbj;
      zf[tid] = (_Float16)tanhf(zp);
    }
    if (tid >= 960 && st + 1 < Sn) {     // commit x(t+1); safe after B1
      h2 p; p[0] = (_Float16)xv.x; p[1] = (_Float16)xv.y;
      *(h2*)&xh[2 * (tid - 960)] = p;
    }
    __syncthreads();                     // B2: zf ready

    // ---- H: col n = tid of [ff1|ff2|ta|tb], K=256 ----
    float b0 = 0.f, b1 = 0.f, b2 = 0.f, b3 = 0.f;
    // streamed chunks first: get the 12 L2 loads in flight, then do the
    // latency-free reg/LDS work while they return
    float s0 = 0.f, s1 = 0.f, s2 = 0.f, s3 = 0.f;
#pragma unroll 4
    for (int c = NV + NL; c < 32; ++c) {
      h8 v = *(const h8*)&zf[c * 8];
      h8 w = *(const h8*)(gH + (size_t)c * 8192);       // 1 KB/wave contiguous
      dot8_4(v, w, s0, s1, s2, s3);
    }
    // VGPR-resident chunks (pinned)
#pragma unroll
    for (int c = 0; c < NV; ++c) {
      h8 v = *(const h8*)&zf[c * 8];                    // LDS broadcast
      dot8_4(v, wH[c], b0, b1, b2, b3);
    }
    // LDS-resident chunks
#pragma unroll
    for (int cc = 0; cc < NL; ++cc) {
      h8 v = *(const h8*)&zf[(NV + cc) * 8];
      h8 w = *(const h8*)(sWH + (size_t)cc * 8192 + tid * 8);
      dot8_4(v, w, b0, b1, b2, b3);
    }
    float g = (b0 + s0) + (b1 + s1) + (b2 + s2) + (b3 + s3) + bH;
    if (tid >= 256) scrH[tid - 256] = g;
    __syncthreads();                     // B3: scrH ready
    if (tid < 256) {
      float ff2 = scrH[tid], ta = scrH[256 + tid], tb = scrH[512 + tid];
      float tt = tsb[st];
      float sg = 1.f / (1.f + __expf(-(ta * tt + tb)));
      float hn = tanhf(g) * (1.f - sg) + sg * tanhf(ff2);
      xh[128 + tid] = (_Float16)hn;
      if (!INLINE_Y)
        hbuf[((size_t)b * Sn + st) * Hn + tid] = (_Float16)hn;
    }
    __syncthreads();                     // B4: h ready

    if (INLINE_Y) {
      // ---- Y: y = h @ Wout + bo, K split 8 ways ----
      float y0 = 0.f, y1 = 0.f, y2 = 0.f, y3 = 0.f;
#pragma unroll
      for (int c = 0; c < 4; ++c) {
        h8 v = *(const h8*)&xh[128 + (kq * 4 + c) * 8];
        h8 w = *(const h8*)(gY + (size_t)c * 1024);
        dot8_4(v, w, y0, y1, y2, y3);
      }
      float ys = y0 + y1 + y2 + y3;
      if (tid >= 128) scrY[tid - 128] = ys;
      __syncthreads();                   // B5
      if (tid < 128) {
        float y = ys + boj;
#pragma unroll
        for (int p = 0; p < 7; ++p) y += scrY[128 * p + tid];
        orow[(size_t)st * FOUT + tid] = y;
      }
    }
  }
}

// Phase 2 (split path): y[BS,128] = h[BS,256] @ Wout + bo. Wout LDS-resident,
// h rows staged 8 at a time; 512 WGs x 256 threads over all 256 CUs.
#define SMEMY (65536 + 4096)
extern "C" __global__ __launch_bounds__(256, 4)
void ygemm(const _Float16* __restrict__ ws, const float* __restrict__ bo,
           float* __restrict__ out) {
  extern __shared__ char ysm[];
  _Float16* sWo = (_Float16*)ysm;            // 32768 halves
  _Float16* sH  = (_Float16*)(ysm + 65536);  // 8 x 256 halves
  const int tid = threadIdx.x;
  { const uint4* g = (const uint4*)(ws + WO_OFF);
    uint4* l = (uint4*)sWo;
#pragma unroll
    for (int i = 0; i < 16; ++i) l[tid + 256 * i] = g[tid + 256 * i]; }
  const _Float16* hb = ws + HBUF_OFF;
  const int row0 = blockIdx.x * 256;
  const int j = tid & 127, rh = tid >> 7;
  const float boj = bo[j];
  for (int it = 0; it < 32; ++it) {
    const int rbase = row0 + it * 8;
    __syncthreads();                         // sH reads from prev iter done
    ((uint4*)sH)[tid] = ((const uint4*)(hb + (size_t)rbase * 256))[tid];
    __syncthreads();
#pragma unroll
    for (int rr = rh; rr < 8; rr += 2) {
      float y0 = 0.f, y1 = 0.f, y2 = 0.f, y3 = 0.f;
#pragma unroll 4
      for (int c = 0; c < 32; ++c) {
        h8 v = *(const h8*)&sH[rr * 256 + c * 8];       // broadcast
        h8 w = *(const h8*)&sWo[((size_t)c * 128 + j) * 8];
        dot8_4(v, w, y0, y1, y2, y3);
      }
      out[(size_t)(rbase + rr) * 128 + j] = y0 + y1 + y2 + y3 + boj;
    }
  }
}

extern "C" void kernel_launch(void* const* d_in, const int* in_sizes, int n_in,
                              void* d_out, int out_size, void* d_ws, size_t ws_size,
                              hipStream_t stream) {
  const float* x   = (const float*)d_in[0];
  const float* ts  = (const float*)d_in[1];
  const float* Wb  = (const float*)d_in[2];
  const float* bb  = (const float*)d_in[3];
  const float* W1  = (const float*)d_in[4];
  const float* bf1 = (const float*)d_in[5];
  const float* W2  = (const float*)d_in[6];
  const float* bf2 = (const float*)d_in[7];
  const float* W3  = (const float*)d_in[8];
  const float* bta = (const float*)d_in[9];
  const float* W4  = (const float*)d_in[10];
  const float* btb = (const float*)d_in[11];
  const float* Wo  = (const float*)d_in[12];
  const float* bo  = (const float*)d_in[13];
  float* out = (float*)d_out;
  _Float16* ws = (_Float16*)d_ws;

  pack_w<<<WS_HALVES / 256, 256, 0, stream>>>(Wb, W1, W2, W3, W4, Wo, ws);

  if (ws_size >= WS_SPLIT_BYTES) {
    hipFuncSetAttribute((const void*)(cfc3<0>),
                        hipFuncAttributeMaxDynamicSharedMemorySize, DYN_SMEM);
    cfc3<0><<<Bn, NT1, DYN_SMEM, stream>>>(x, ts, bb, bf1, bf2, bta, btb, bo, ws, out);
    hipFuncSetAttribute((const void*)ygemm,
                        hipFuncAttributeMaxDynamicSharedMemorySize, SMEMY);
    ygemm<<<(Bn * Sn) / 256, 256, SMEMY, stream>>>(ws, bo, out);
  } else {
    hipFuncSetAttribute((const void*)(cfc3<1>),
                        hipFuncAttributeMaxDynamicSharedMemorySize, DYN_SMEM);
    cfc3<1><<<Bn, NT1, DYN_SMEM, stream>>>(x, ts, bb, bf1, bf2, bta, btb, bo, ws, out);
  }
}